// Round 14
// baseline (188.065 us; speedup 1.0000x reference)
//
#include <hip/hip_runtime.h>
#include <math.h>

// Problem constants
#define CCH   640          // channels
#define MM    25           // m = 5*5 spatial
#define NB    4096         // query batch
#define WSR   25           // way*shot prototype rows
#define ROWF  16000        // CCH*MM floats per row
#define SLAB  (NB*CCH)     // 2,621,440 floats = one output slab (per w)
#define WELEM (CCH*CCH)    // 409600
#define NMEAN ((WSR+NB)*CCH)
#define NMEAN_B ((NMEAN + 255)/256)     // 10303
#define NW_B  (WELEM/256)               // 1600 blocks, 4 floats/thread over 4 mats

typedef float fx4 __attribute__((ext_vector_type(4)));
typedef short bf8 __attribute__((ext_vector_type(8)));   // 8 bf16 bit-patterns
typedef short s4  __attribute__((ext_vector_type(4)));
typedef float f32x4 __attribute__((ext_vector_type(4)));

static __device__ __forceinline__ void load4(float* dst, const float* p) {
  __builtin_memcpy(dst, p, 16);
}
// RNE f32 -> bf16 bit pattern
static __device__ __forceinline__ unsigned short bf16_rne(float x) {
  unsigned u = __builtin_bit_cast(unsigned, x);
  return (unsigned short)((u + 0x7FFFu + ((u >> 16) & 1u)) >> 16);
}
static __device__ __forceinline__ float bfh2f(unsigned short h) {
  return __builtin_bit_cast(float, (unsigned)h << 16);
}

// ---------------------------------------------------------------------------
// prep_k: blocks [0,NMEAN_B): rowmean (R5 form) -> bf16 hi/lo pairs.
//         blocks [NMEAN_B, +NW_B): convert 4 W matrices f32 -> bf16 hi/lo.
// ---------------------------------------------------------------------------
__global__ __launch_bounds__(256) void prep_k(
    const float* __restrict__ spt, const float* __restrict__ qry,
    const float* __restrict__ W_p, const float* __restrict__ W_q,
    const float* __restrict__ W_prt, const float* __restrict__ W_qs,
    short* __restrict__ pmh, short* __restrict__ pml,
    short* __restrict__ qmh, short* __restrict__ qml,
    short* __restrict__ wph, short* __restrict__ wpl,
    short* __restrict__ wqh, short* __restrict__ wql,
    short* __restrict__ wrh, short* __restrict__ wrl,
    short* __restrict__ wsh, short* __restrict__ wsl) {
  const int bid = blockIdx.x;
  if (bid < NMEAN_B) {
    int idx = bid * 256 + threadIdx.x;    // idx = row*CCH + c
    if (idx >= NMEAN) return;
    int row = idx / CCH, c = idx - row * CCH;
    const float* p;
    short *dh, *dl; int off;
    if (row < WSR) { p = spt + (size_t)row * ROWF + c * MM; dh = pmh; dl = pml; off = idx; }
    else {
      p = qry + (size_t)(row - WSR) * ROWF + c * MM;
      dh = qmh; dl = qml; off = idx - WSR*CCH;
    }
    float s = 0.f, v[4];
    #pragma unroll
    for (int j = 0; j < 6; ++j) { load4(v, p + 4*j); s += (v[0]+v[1]) + (v[2]+v[3]); }
    s += p[24];
    s *= (1.f/25.f);
    unsigned short hb = bf16_rne(s);
    dh[off] = (short)hb;
    dl[off] = (short)bf16_rne(s - bfh2f(hb));
  } else {
    int t = (bid - NMEAN_B) * 256 + threadIdx.x;   // 0..409599
    int mi = t / (WELEM/4);
    int ei = (t - mi * (WELEM/4)) * 4;
    const float* W = (mi==0) ? W_p : (mi==1) ? W_q : (mi==2) ? W_prt : W_qs;
    short* dh = (mi==0) ? wph : (mi==1) ? wqh : (mi==2) ? wrh : wsh;
    short* dl = (mi==0) ? wpl : (mi==1) ? wql : (mi==2) ? wrl : wsl;
    fx4 v = *(const fx4*)(W + ei);
    s4 h, l;
    #pragma unroll
    for (int e = 0; e < 4; ++e) {
      unsigned short hb = bf16_rne(v[e]);
      h[e] = (short)hb;
      l[e] = (short)bf16_rne(v[e] - bfh2f(hb));
    }
    *(s4*)(dh + ei) = h;
    *(s4*)(dl + ei) = l;
  }
}

// ---------------------------------------------------------------------------
// rowmean_all (f32 out) — fallback path only.
// ---------------------------------------------------------------------------
__global__ __launch_bounds__(256) void rowmean_all_k(
    const float* __restrict__ spt, const float* __restrict__ qry,
    float* __restrict__ pmean, float* __restrict__ qmean, int n) {
  int idx = blockIdx.x * 256 + threadIdx.x;
  if (idx >= n) return;
  int row = idx / CCH, c = idx - row * CCH;
  const float* p;
  float* dst;
  if (row < WSR) { p = spt + (size_t)row * ROWF + c * MM; dst = pmean + idx; }
  else { p = qry + (size_t)(row - WSR) * ROWF + c * MM; dst = qmean + idx - WSR*CCH; }
  float s = 0.f, v[4];
  #pragma unroll
  for (int j = 0; j < 6; ++j) { load4(v, p + 4*j); s += (v[0]+v[1]) + (v[2]+v[3]); }
  s += p[24];
  *dst = s * (1.f/25.f);
}

// ---------------------------------------------------------------------------
// gemm2_bf_k — R14: 32x64 tile, 2x2 waves (16x32 per wave, acc[2]), BK=64.
// 1290 blocks -> ~5 blocks/CU, ~20 waves/CU: barrier drains hidden by other
// blocks. global_load_lds width-16, linear LDS dest, source-swizzled (rule 21);
// read XORs the same involution. 24 KB LDS. OOB A-rows (proto) read garbage
// inside d_ws — safe: MFMA C-rows independent, rows >= M never written.
// Blocks [0,10): proto (M0 rows); [10,1290): query (4096 rows, 128x10 tiles).
// ---------------------------------------------------------------------------
__global__ __launch_bounds__(256) void gemm2_bf_k(
    const short* __restrict__ Ah0, const short* __restrict__ Al0,
    const short* __restrict__ Wh0, const short* __restrict__ Wl0,
    const float* __restrict__ g0, const float* __restrict__ b0,
    const float* __restrict__ rm0, const float* __restrict__ rv0,
    int M0, float* __restrict__ out0,
    const short* __restrict__ Ah1, const short* __restrict__ Al1,
    const short* __restrict__ Wh1, const short* __restrict__ Wl1,
    const float* __restrict__ g1, const float* __restrict__ b1,
    const float* __restrict__ rm1, const float* __restrict__ rv1,
    int M1, float* __restrict__ out1) {
  __shared__ short sAh[32*64], sAl[32*64], sWh[64*64], sWl[64*64];   // 24 KB
  const int bid = blockIdx.x;
  const short *Ah, *Al, *Wh, *Wl;
  const float *gg, *bb, *rm, *rv;
  float* out;
  int M, i0, j0;
  if (bid < 10) {
    Ah=Ah0; Al=Al0; Wh=Wh0; Wl=Wl0; gg=g0; bb=b0; rm=rm0; rv=rv0; out=out0; M=M0;
    i0 = 0; j0 = bid * 64;
  } else {
    int b2 = bid - 10;
    Ah=Ah1; Al=Al1; Wh=Wh1; Wl=Wl1; gg=g1; bb=b1; rm=rm1; rv=rv1; out=out1; M=M1;
    i0 = (b2 / 10) * 32; j0 = (b2 % 10) * 64;
  }
  const int tid  = threadIdx.x;
  const int wave = tid >> 6, lane = tid & 63;
  const int lrow = lane & 15, lk = lane >> 4;
  const int wr = wave >> 1, wc = wave & 1;       // 2x2 wave grid

  f32x4 acc[2] = {{0.f,0.f,0.f,0.f},{0.f,0.f,0.f,0.f}};

  const int lrow8 = lane >> 3;       // 0..7 (row within 8-row issue group)
  const int spos  = lane & 7;        // linear 16B chunk within row

  for (int kt = 0; kt < CCH; kt += 64) {
    // ---- stage 24 KB via 24 glds issues; wave w handles idx w*6..w*6+5 ----
    // idx 0..3 -> sAh, 4..7 -> sAl, 8..15 -> sWh, 16..23 -> sWl
    #pragma unroll
    for (int ii = 0; ii < 6; ++ii) {
      int idx = wave * 6 + ii;
      const short* gb; short* lb; int rbase, sub;
      if (idx < 4)       { gb = Ah; lb = sAh; rbase = i0; sub = idx; }
      else if (idx < 8)  { gb = Al; lb = sAl; rbase = i0; sub = idx - 4; }
      else if (idx < 16) { gb = Wh; lb = sWh; rbase = j0; sub = idx - 8; }
      else               { gb = Wl; lb = sWl; rbase = j0; sub = idx - 16; }
      int row = sub * 8 + lrow8;
      int gch = spos ^ (row & 7);    // inverse swizzle on global chunk
      const short* g = gb + (size_t)(rbase + row) * CCH + kt + gch * 8;
      __builtin_amdgcn_global_load_lds(
          (const __attribute__((address_space(1))) unsigned int*)g,
          (__attribute__((address_space(3))) unsigned int*)(lb + sub * 512),
          16, 0, 0);
    }
    __syncthreads();
    // ---- MFMA: LDS[row][c] = G[row][c^(row&7)] -> read at c=slot^(row&7) ----
    #pragma unroll
    for (int ks = 0; ks < 2; ++ks) {
      const int arow = wr * 16 + lrow;           // 0..31
      const int slot = ks * 4 + lk;
      const int aoff = arow * 64 + ((slot ^ (arow & 7)) << 3);
      bf8 afh = *(const bf8*)&sAh[aoff];
      bf8 afl = *(const bf8*)&sAl[aoff];
      #pragma unroll
      for (int n = 0; n < 2; ++n) {
        const int wrow = wc * 32 + n * 16 + lrow;  // 0..63
        const int woff = wrow * 64 + ((slot ^ (wrow & 7)) << 3);
        bf8 wfh = *(const bf8*)&sWh[woff];
        bf8 wfl = *(const bf8*)&sWl[woff];
        acc[n] = __builtin_amdgcn_mfma_f32_16x16x32_bf16(afh, wfh, acc[n], 0, 0, 0);
        acc[n] = __builtin_amdgcn_mfma_f32_16x16x32_bf16(afl, wfh, acc[n], 0, 0, 0);
        acc[n] = __builtin_amdgcn_mfma_f32_16x16x32_bf16(afh, wfl, acc[n], 0, 0, 0);
      }
    }
    __syncthreads();
  }
  #pragma unroll
  for (int n = 0; n < 2; ++n) {
    int j = j0 + wc * 32 + n * 16 + lrow;
    float s  = rsqrtf(rv[j] + 1e-5f) * gg[j];
    float sh = bb[j] - rm[j] * s;
    #pragma unroll
    for (int r = 0; r < 4; ++r) {
      int row = i0 + wr * 16 + lk * 4 + r;
      if (row < M)
        out[(size_t)row * CCH + j] = 1.f + tanhf(fmaf(acc[n][r], s, sh));
    }
  }
}

// ---------------------------------------------------------------------------
// gemm2_k — MFMA with in-kernel conversion (fallback path only, 64x64 tile).
// ---------------------------------------------------------------------------
__global__ __launch_bounds__(256) void gemm2_k(
    const float* __restrict__ A0, const float* __restrict__ W0,
    const float* __restrict__ g0, const float* __restrict__ b0,
    const float* __restrict__ rm0, const float* __restrict__ rv0,
    int M0, float* __restrict__ out0,
    const float* __restrict__ A1, const float* __restrict__ W1,
    const float* __restrict__ g1, const float* __restrict__ b1,
    const float* __restrict__ rm1, const float* __restrict__ rv1,
    int M1, float* __restrict__ out1) {
  __shared__ short Ah[64*64], Al[64*64], Wh[64*64], Wl[64*64];
  const int bid = blockIdx.x;
  const float *A, *W, *gg, *bb, *rm, *rv;
  float* out;
  int M, i0, j0;
  if (bid < 10) {
    A = A0; W = W0; gg = g0; bb = b0; rm = rm0; rv = rv0; out = out0; M = M0;
    i0 = 0; j0 = bid * 64;
  } else {
    int b2 = bid - 10;
    A = A1; W = W1; gg = g1; bb = b1; rm = rm1; rv = rv1; out = out1; M = M1;
    i0 = (b2 / 10) * 64; j0 = (b2 % 10) * 64;
  }
  const int tid  = threadIdx.x;
  const int wave = tid >> 6, lane = tid & 63;
  const int lrow = lane & 15, lk = lane >> 4;
  f32x4 acc[4] = {{0.f,0.f,0.f,0.f},{0.f,0.f,0.f,0.f},
                  {0.f,0.f,0.f,0.f},{0.f,0.f,0.f,0.f}};
  const int srow0 = tid >> 3;
  const int sslot = tid & 7;
  for (int kt = 0; kt < CCH; kt += 64) {
    #pragma unroll
    for (int rnd = 0; rnd < 2; ++rnd) {
      int row  = srow0 + rnd * 32;
      int soff = row * 64 + ((sslot ^ (row & 7)) << 3);
      float a8[8];
      if (i0 + row < M) {
        const float* ap = A + (size_t)(i0 + row) * CCH + kt + sslot * 8;
        load4(a8, ap); load4(a8 + 4, ap + 4);
      } else {
        #pragma unroll
        for (int e = 0; e < 8; ++e) a8[e] = 0.f;
      }
      bf8 hv, lv;
      #pragma unroll
      for (int e = 0; e < 8; ++e) {
        unsigned short hb = bf16_rne(a8[e]);
        hv[e] = (short)hb;
        lv[e] = (short)bf16_rne(a8[e] - bfh2f(hb));
      }
      *(bf8*)&Ah[soff] = hv;
      *(bf8*)&Al[soff] = lv;
      float w8[8];
      const float* wp_ = W + (size_t)(j0 + row) * CCH + kt + sslot * 8;
      load4(w8, wp_); load4(w8 + 4, wp_ + 4);
      #pragma unroll
      for (int e = 0; e < 8; ++e) {
        unsigned short hb = bf16_rne(w8[e]);
        hv[e] = (short)hb;
        lv[e] = (short)bf16_rne(w8[e] - bfh2f(hb));
      }
      *(bf8*)&Wh[soff] = hv;
      *(bf8*)&Wl[soff] = lv;
    }
    __syncthreads();
    #pragma unroll
    for (int ks = 0; ks < 2; ++ks) {
      const int arow = wave * 16 + lrow;
      const int slot = ks * 4 + lk;
      const int aoff = arow * 64 + ((slot ^ (arow & 7)) << 3);
      bf8 afh = *(const bf8*)&Ah[aoff];
      bf8 afl = *(const bf8*)&Al[aoff];
      #pragma unroll
      for (int n = 0; n < 4; ++n) {
        const int wrow = n * 16 + lrow;
        const int woff = wrow * 64 + ((slot ^ (wrow & 7)) << 3);
        bf8 wfh = *(const bf8*)&Wh[woff];
        bf8 wfl = *(const bf8*)&Wl[woff];
        acc[n] = __builtin_amdgcn_mfma_f32_16x16x32_bf16(afh, wfh, acc[n], 0, 0, 0);
        acc[n] = __builtin_amdgcn_mfma_f32_16x16x32_bf16(afl, wfh, acc[n], 0, 0, 0);
        acc[n] = __builtin_amdgcn_mfma_f32_16x16x32_bf16(afh, wfl, acc[n], 0, 0, 0);
      }
    }
    __syncthreads();
  }
  #pragma unroll
  for (int n = 0; n < 4; ++n) {
    int j = j0 + n * 16 + lrow;
    float s  = rsqrtf(rv[j] + 1e-5f) * gg[j];
    float sh = bb[j] - rm[j] * s;
    #pragma unroll
    for (int r = 0; r < 4; ++r) {
      int row = i0 + wave * 16 + lk * 4 + r;
      if (row < M)
        out[(size_t)row * CCH + j] = 1.f + tanhf(fmaf(acc[n][r], s, sh));
    }
  }
}

// ---------------------------------------------------------------------------
// pcd_all — R11 structure (forward order; element-wise lane-pair pre-reduce).
// ---------------------------------------------------------------------------
template<bool BF>
__global__ __launch_bounds__(320, 4) void pcd_all_k(
    const float* __restrict__ spt, const float* __restrict__ qry,
    const float* __restrict__ sbuf, const float* __restrict__ qg,
    const float* __restrict__ cw_p, const float* __restrict__ cb_p,
    const float* __restrict__ cw_q, const float* __restrict__ cb_q,
    float* __restrict__ nd1f, float* __restrict__ nd2f,
    short* __restrict__ nd1h, short* __restrict__ nd1l,
    short* __restrict__ nd2h, short* __restrict__ nd2l) {
  const int blk = blockIdx.x;
  const int t = threadIdx.x;
  const float *row, *scl, *cw, *cbp;
  float* ndf; short *ndh, *ndl;
  if (blk < WSR) {
    row = spt + (size_t)blk * ROWF; scl = sbuf + (size_t)blk * CCH;
    cw = cw_p; cbp = cb_p;
    ndf = nd1f ? nd1f + (size_t)blk * CCH : nullptr;
    ndh = nd1h + (size_t)blk * CCH; ndl = nd1l + (size_t)blk * CCH;
  } else {
    int b = blk - WSR;
    row = qry + (size_t)b * ROWF; scl = qg + (size_t)b * CCH;
    cw = cw_q; cbp = cb_q;
    ndf = nd2f ? nd2f + (size_t)b * CCH : nullptr;
    ndh = nd2h + (size_t)b * CCH; ndl = nd2l + (size_t)b * CCH;
  }
  __shared__ float xps[160 * MM];    // 16 KB pair-row transpose buffer
  __shared__ float part[10][MM];
  __shared__ float pooled[2][MM];
  __shared__ float vbuf[MM];

  const float sc0 = scl[t];
  const float sc1 = scl[t + 320];
  const int tp = t >> 1;
  const bool even = !(t & 1);

  float x0[MM], x1[MM];
  {
    const float* p0 = row + t * MM;
    const float* p1 = row + (t + 320) * MM;
    float v[4];
    #pragma unroll
    for (int j = 0; j < 6; ++j) {
      load4(v, p0 + 4*j);
      x0[4*j+0] = v[0]*sc0; x0[4*j+1] = v[1]*sc0; x0[4*j+2] = v[2]*sc0; x0[4*j+3] = v[3]*sc0;
    }
    x0[24] = p0[24] * sc0;
    #pragma unroll
    for (int j = 0; j < 6; ++j) {
      load4(v, p1 + 4*j);
      x1[4*j+0] = v[0]*sc1; x1[4*j+1] = v[1]*sc1; x1[4*j+2] = v[2]*sc1; x1[4*j+3] = v[3]*sc1;
    }
    x1[24] = p1[24] * sc1;
  }

  // ---- round 1: max (element-wise pair pre-reduce, scalar temps) ----
  #pragma unroll
  for (int p = 0; p < MM; ++p) {
    float m = fmaxf(x0[p], x1[p]);
    m = fmaxf(m, __shfl_xor(m, 1));
    if (even) xps[tp*MM + p] = m;
  }
  __syncthreads();
  if (t < 250) {
    int g = t / MM, p = t - g * MM;   // g: 0..9, 16 pair-rows each
    float m = -3.4e38f;
    #pragma unroll
    for (int k = 0; k < 16; ++k) m = fmaxf(m, xps[(g*16 + k)*MM + p]);
    part[g][p] = m;
  }
  __syncthreads();
  if (t < MM) {
    float m = -3.4e38f;
    #pragma unroll
    for (int g = 0; g < 10; ++g) m = fmaxf(m, part[g][t]);
    pooled[0][t] = m;
  }
  // ---- round 2: sum ----
  #pragma unroll
  for (int p = 0; p < MM; ++p) {
    float s = x0[p] + x1[p];
    s += __shfl_xor(s, 1);
    if (even) xps[tp*MM + p] = s;
  }
  __syncthreads();
  if (t < 250) {
    int g = t / MM, p = t - g * MM;
    float s = 0.f;
    #pragma unroll
    for (int k = 0; k < 16; ++k) s += xps[(g*16 + k)*MM + p];
    part[g][p] = s;
  }
  __syncthreads();
  if (t < MM) {
    float s = 0.f;
    #pragma unroll
    for (int g = 0; g < 10; ++g) s += part[g][t];
    pooled[1][t] = s * (1.f/640.f);
  }
  __syncthreads();
  // ---- 3x3 conv + sigmoid (25 threads) ----
  if (t < MM) {
    int h = t / 5, w_ = t % 5;
    float y = cbp[0];
    #pragma unroll
    for (int ci = 0; ci < 2; ++ci)
      #pragma unroll
      for (int kh = 0; kh < 3; ++kh)
        #pragma unroll
        for (int kw = 0; kw < 3; ++kw) {
          int hh = h + kh - 1, ww = w_ + kw - 1;
          if (hh >= 0 && hh < 5 && ww >= 0 && ww < 5)
            y += pooled[ci][hh*5 + ww] * cw[ci*9 + kh*3 + kw];
        }
    vbuf[t] = 1.f / (1.f + expf(-y));
  }
  __syncthreads();
  // ---- distance from registers ----
  float d0 = 0.f, d1 = 0.f;
  #pragma unroll
  for (int p = 0; p < MM; ++p) {
    float v = vbuf[p];
    float a = x0[p] - v; d0 = fmaf(a, a, d0);
    float e = x1[p] - v; d1 = fmaf(e, e, d1);
  }
  if (BF) {
    float n0 = -d0, n1 = -d1;
    unsigned short h0 = bf16_rne(n0), h1 = bf16_rne(n1);
    ndh[t]       = (short)h0;
    ndl[t]       = (short)bf16_rne(n0 - bfh2f(h0));
    ndh[t + 320] = (short)h1;
    ndl[t + 320] = (short)bf16_rne(n1 - bfh2f(h1));
  } else {
    ndf[t]       = -d0;
    ndf[t + 320] = -d1;
  }
}

// ---------------------------------------------------------------------------
// combine (R5 form): slab-sequential streaming, NT stores.
// ---------------------------------------------------------------------------
__global__ __launch_bounds__(256) void combine_k(const float* __restrict__ wq,
    const float* __restrict__ wp, float* __restrict__ out) {
  const unsigned S4 = SLAB / 4;
  unsigned idx = blockIdx.x * 256 + threadIdx.x;
  unsigned w = idx / S4;
  unsigned rem = idx - w * S4;
  int c = (int)((rem * 4) % CCH);
  fx4 q = ((const fx4*)wq)[rem];
  fx4 p = *(const fx4*)(wp + w*CCH + c);
  fx4 o = 0.5f * (q + p);
  __builtin_nontemporal_store(o, (fx4*)out + idx);
}

__global__ __launch_bounds__(256) void combine24_k(const float* __restrict__ wq,
    const float* __restrict__ wp, float* __restrict__ out) {
  const size_t S4 = (size_t)SLAB / 4;
  size_t idx = (size_t)blockIdx.x * 256 + threadIdx.x;
  int slot = (int)(idx / S4);
  size_t rem = idx - (size_t)slot * S4;
  int w = (slot < 3) ? slot : slot + 1;
  int c = (int)((rem * 4) % CCH);
  float4 q = ((const float4*)wq)[rem];
  float4 p = *(const float4*)(wp + w*CCH + c);
  float4 o;
  o.x = 0.5f*(q.x + p.x); o.y = 0.5f*(q.y + p.y);
  o.z = 0.5f*(q.z + p.z); o.w = 0.5f*(q.w + p.w);
  ((float4*)out)[(size_t)w * S4 + rem] = o;
}

__global__ __launch_bounds__(256) void combine3_k(const float* __restrict__ wp,
                                                  float* __restrict__ out) {
  const size_t S4 = (size_t)SLAB / 4;
  size_t rem = (size_t)blockIdx.x * 256 + threadIdx.x;
  int c = (int)((rem * 4) % CCH);
  float4* ptr = (float4*)out + 3 * S4 + rem;
  float4 q = *ptr;
  float4 p = *(const float4*)(wp + 3*CCH + c);
  float4 o;
  o.x = 0.5f*(q.x + p.x); o.y = 0.5f*(q.y + p.y);
  o.z = 0.5f*(q.z + p.z); o.w = 0.5f*(q.w + p.w);
  *ptr = o;
}

// ---------------------------------------------------------------------------
extern "C" void kernel_launch(void* const* d_in, const int* in_sizes, int n_in,
                              void* d_out, int out_size, void* d_ws, size_t ws_size,
                              hipStream_t stream) {
  const float* spt    = (const float*)d_in[0];
  const float* qry    = (const float*)d_in[1];
  const float* W_p    = (const float*)d_in[2];
  const float* g_p    = (const float*)d_in[3];
  const float* b_p    = (const float*)d_in[4];
  const float* rm_p   = (const float*)d_in[5];
  const float* rv_p   = (const float*)d_in[6];
  const float* W_q    = (const float*)d_in[7];
  const float* g_q    = (const float*)d_in[8];
  const float* b_q    = (const float*)d_in[9];
  const float* rm_q   = (const float*)d_in[10];
  const float* rv_q   = (const float*)d_in[11];
  const float* W_prt  = (const float*)d_in[12];
  const float* g_prt  = (const float*)d_in[13];
  const float* b_prt  = (const float*)d_in[14];
  const float* rm_prt = (const float*)d_in[15];
  const float* rv_prt = (const float*)d_in[16];
  const float* W_qs   = (const float*)d_in[17];
  const float* g_qs   = (const float*)d_in[18];
  const float* b_qs   = (const float*)d_in[19];
  const float* rm_qs  = (const float*)d_in[20];
  const float* rv_qs  = (const float*)d_in[21];
  const float* cw_p   = (const float*)d_in[22];
  const float* cb_p   = (const float*)d_in[23];
  const float* cw_q   = (const float*)d_in[24];
  const float* cb_q   = (const float*)d_in[25];

  float* outp = (float*)d_out;
  float* ws   = (float*)d_ws;

  dim3 blk(256);
  dim3 blkp(320);

  const size_t fl_count = 32000 + 2*(size_t)SLAB;
  const size_t sh_count = 4*16000 + 4*(size_t)SLAB + 8*(size_t)WELEM;
  const size_t need = fl_count*sizeof(float) + sh_count*sizeof(short);
  const bool big_ws = ws_size >= need;

  if (big_ws) {
    float* sbuf = ws;
    float* wprt = ws + 16000;
    float* qg   = ws + 32000;
    float* wqry = ws + 32000 + (size_t)SLAB;
    short* sp   = (short*)(ws + fl_count);
    short* pmh  = sp;            short* pml  = sp + 16000;
    short* nd1h = sp + 32000;    short* nd1l = sp + 48000;
    short* qmh  = sp + 64000;
    short* qml  = qmh + (size_t)SLAB;
    short* nd2h = qml + (size_t)SLAB;
    short* nd2l = nd2h + (size_t)SLAB;
    short* wph  = nd2l + (size_t)SLAB;
    short* wpl  = wph + WELEM;
    short* wqh  = wpl + WELEM;  short* wql = wqh + WELEM;
    short* wrh  = wql + WELEM;  short* wrl = wrh + WELEM;
    short* wsh  = wrl + WELEM;  short* wsl = wsh + WELEM;

    prep_k<<<NMEAN_B + NW_B, blk, 0, stream>>>(spt, qry, W_p, W_q, W_prt, W_qs,
        pmh, pml, qmh, qml, wph, wpl, wqh, wql, wrh, wrl, wsh, wsl);
    gemm2_bf_k<<<10 + (NB/32)*10, blk, 0, stream>>>(
        pmh, pml, wph, wpl, g_p, b_p, rm_p, rv_p, WSR, sbuf,
        qmh, qml, wqh, wql, g_q, b_q, rm_q, rv_q, NB, qg);
    pcd_all_k<true><<<WSR + NB, blkp, 0, stream>>>(spt, qry, sbuf, qg,
        cw_p, cb_p, cw_q, cb_q, nullptr, nullptr, nd1h, nd1l, nd2h, nd2l);
    gemm2_bf_k<<<10 + (NB/32)*10, blk, 0, stream>>>(
        nd1h, nd1l, wrh, wrl, g_prt, b_prt, rm_prt, rv_prt, WSR, wprt,
        nd2h, nd2l, wsh, wsl, g_qs, b_qs, rm_qs, rv_qs, NB, wqry);
    combine_k<<<25 * (SLAB/4) / 256, blk, 0, stream>>>(wqry, wprt, outp);
  } else {
    // fallback: R8 pipeline staged in d_out slabs + small ws buffers
    float* pmean  = ws;
    float* sbuf   = ws + 16000;
    float* ndist1 = ws + 32000;
    float* wprt   = ws + 48000;
    float* qmean  = outp + 0 * (size_t)SLAB;
    float* qg     = outp + 1 * (size_t)SLAB;
    float* ndist2 = outp + 2 * (size_t)SLAB;
    float* wqry   = outp + 3 * (size_t)SLAB;
    const int nmean = (WSR + NB) * CCH;
    rowmean_all_k<<<(nmean + 255)/256, blk, 0, stream>>>(spt, qry, pmean, qmean, nmean);
    gemm2_k<<<650, blk, 0, stream>>>(pmean, W_p, g_p, b_p, rm_p, rv_p, WSR, sbuf,
                                     qmean, W_q, g_q, b_q, rm_q, rv_q, NB, qg);
    pcd_all_k<false><<<WSR + NB, blkp, 0, stream>>>(spt, qry, sbuf, qg,
        cw_p, cb_p, cw_q, cb_q, ndist1, ndist2,
        (short*)ws, (short*)ws, (short*)ws, (short*)ws);
    gemm2_k<<<650, blk, 0, stream>>>(ndist1, W_prt, g_prt, b_prt, rm_prt, rv_prt, WSR, wprt,
                                     ndist2, W_qs, g_qs, b_qs, rm_qs, rv_qs, NB, wqry);
    combine24_k<<<(24 * (SLAB/4)) / 256, blk, 0, stream>>>(wqry, wprt, outp);
    combine3_k<<<(SLAB/4) / 256, blk, 0, stream>>>(wprt, outp);
  }
}

// Round 15
// 179.635 us; speedup vs baseline: 1.0469x; 1.0469x over previous
//
#include <hip/hip_runtime.h>
#include <math.h>

// Problem constants
#define CCH   640          // channels
#define MM    25           // m = 5*5 spatial
#define NB    4096         // query batch
#define WSR   25           // way*shot prototype rows
#define ROWF  16000        // CCH*MM floats per row
#define SLAB  (NB*CCH)     // 2,621,440 floats = one output slab (per w)
#define WELEM (CCH*CCH)    // 409600
#define NMEAN ((WSR+NB)*CCH)
#define NMEAN_B ((NMEAN + 255)/256)     // 10303
#define NW_B  (WELEM/256)               // 1600 blocks, 4 floats/thread over 4 mats

typedef float fx4 __attribute__((ext_vector_type(4)));
typedef short bf8 __attribute__((ext_vector_type(8)));   // 8 bf16 bit-patterns
typedef short s4  __attribute__((ext_vector_type(4)));
typedef float f32x4 __attribute__((ext_vector_type(4)));

static __device__ __forceinline__ void load4(float* dst, const float* p) {
  __builtin_memcpy(dst, p, 16);
}
// RNE f32 -> bf16 bit pattern
static __device__ __forceinline__ unsigned short bf16_rne(float x) {
  unsigned u = __builtin_bit_cast(unsigned, x);
  return (unsigned short)((u + 0x7FFFu + ((u >> 16) & 1u)) >> 16);
}
static __device__ __forceinline__ float bfh2f(unsigned short h) {
  return __builtin_bit_cast(float, (unsigned)h << 16);
}

// ---------------------------------------------------------------------------
// prep_k: blocks [0,NMEAN_B): rowmean (R5 form) -> bf16 hi/lo pairs.
//         blocks [NMEAN_B, +NW_B): convert 4 W matrices f32 -> bf16 hi/lo.
// ---------------------------------------------------------------------------
__global__ __launch_bounds__(256) void prep_k(
    const float* __restrict__ spt, const float* __restrict__ qry,
    const float* __restrict__ W_p, const float* __restrict__ W_q,
    const float* __restrict__ W_prt, const float* __restrict__ W_qs,
    short* __restrict__ pmh, short* __restrict__ pml,
    short* __restrict__ qmh, short* __restrict__ qml,
    short* __restrict__ wph, short* __restrict__ wpl,
    short* __restrict__ wqh, short* __restrict__ wql,
    short* __restrict__ wrh, short* __restrict__ wrl,
    short* __restrict__ wsh, short* __restrict__ wsl) {
  const int bid = blockIdx.x;
  if (bid < NMEAN_B) {
    int idx = bid * 256 + threadIdx.x;    // idx = row*CCH + c
    if (idx >= NMEAN) return;
    int row = idx / CCH, c = idx - row * CCH;
    const float* p;
    short *dh, *dl; int off;
    if (row < WSR) { p = spt + (size_t)row * ROWF + c * MM; dh = pmh; dl = pml; off = idx; }
    else {
      p = qry + (size_t)(row - WSR) * ROWF + c * MM;
      dh = qmh; dl = qml; off = idx - WSR*CCH;
    }
    float s = 0.f, v[4];
    #pragma unroll
    for (int j = 0; j < 6; ++j) { load4(v, p + 4*j); s += (v[0]+v[1]) + (v[2]+v[3]); }
    s += p[24];
    s *= (1.f/25.f);
    unsigned short hb = bf16_rne(s);
    dh[off] = (short)hb;
    dl[off] = (short)bf16_rne(s - bfh2f(hb));
  } else {
    int t = (bid - NMEAN_B) * 256 + threadIdx.x;   // 0..409599
    int mi = t / (WELEM/4);
    int ei = (t - mi * (WELEM/4)) * 4;
    const float* W = (mi==0) ? W_p : (mi==1) ? W_q : (mi==2) ? W_prt : W_qs;
    short* dh = (mi==0) ? wph : (mi==1) ? wqh : (mi==2) ? wrh : wsh;
    short* dl = (mi==0) ? wpl : (mi==1) ? wql : (mi==2) ? wrl : wsl;
    fx4 v = *(const fx4*)(W + ei);
    s4 h, l;
    #pragma unroll
    for (int e = 0; e < 4; ++e) {
      unsigned short hb = bf16_rne(v[e]);
      h[e] = (short)hb;
      l[e] = (short)bf16_rne(v[e] - bfh2f(hb));
    }
    *(s4*)(dh + ei) = h;
    *(s4*)(dl + ei) = l;
  }
}

// ---------------------------------------------------------------------------
// rowmean_all (f32 out) — fallback path only.
// ---------------------------------------------------------------------------
__global__ __launch_bounds__(256) void rowmean_all_k(
    const float* __restrict__ spt, const float* __restrict__ qry,
    float* __restrict__ pmean, float* __restrict__ qmean, int n) {
  int idx = blockIdx.x * 256 + threadIdx.x;
  if (idx >= n) return;
  int row = idx / CCH, c = idx - row * CCH;
  const float* p;
  float* dst;
  if (row < WSR) { p = spt + (size_t)row * ROWF + c * MM; dst = pmean + idx; }
  else { p = qry + (size_t)(row - WSR) * ROWF + c * MM; dst = qmean + idx - WSR*CCH; }
  float s = 0.f, v[4];
  #pragma unroll
  for (int j = 0; j < 6; ++j) { load4(v, p + 4*j); s += (v[0]+v[1]) + (v[2]+v[3]); }
  s += p[24];
  *dst = s * (1.f/25.f);
}

// ---------------------------------------------------------------------------
// gemm2_bf_k — R13 form (measured best): 64x64 tile, BK=64, global_load_lds
// width-16 staging; linear LDS dest, source-swizzled (rule 21); read XORs the
// same involution. Each wave stages one of the 4 arrays. OOB proto A-rows
// read garbage inside d_ws — safe (rows >= M never written).
// ---------------------------------------------------------------------------
__global__ __launch_bounds__(256) void gemm2_bf_k(
    const short* __restrict__ Ah0, const short* __restrict__ Al0,
    const short* __restrict__ Wh0, const short* __restrict__ Wl0,
    const float* __restrict__ g0, const float* __restrict__ b0,
    const float* __restrict__ rm0, const float* __restrict__ rv0,
    int M0, float* __restrict__ out0,
    const short* __restrict__ Ah1, const short* __restrict__ Al1,
    const short* __restrict__ Wh1, const short* __restrict__ Wl1,
    const float* __restrict__ g1, const float* __restrict__ b1,
    const float* __restrict__ rm1, const float* __restrict__ rv1,
    int M1, float* __restrict__ out1) {
  __shared__ short sAh[64*64], sAl[64*64], sWh[64*64], sWl[64*64];   // 32 KB
  const int bid = blockIdx.x;
  const short *Ah, *Al, *Wh, *Wl;
  const float *gg, *bb, *rm, *rv;
  float* out;
  int M, i0, j0;
  if (bid < 10) {
    Ah=Ah0; Al=Al0; Wh=Wh0; Wl=Wl0; gg=g0; bb=b0; rm=rm0; rv=rv0; out=out0; M=M0;
    i0 = 0; j0 = bid * 64;
  } else {
    int b2 = bid - 10;
    Ah=Ah1; Al=Al1; Wh=Wh1; Wl=Wl1; gg=g1; bb=b1; rm=rm1; rv=rv1; out=out1; M=M1;
    i0 = (b2 / 10) * 64; j0 = (b2 % 10) * 64;
  }
  const int tid  = threadIdx.x;
  const int wave = tid >> 6, lane = tid & 63;
  const int lrow = lane & 15, lk = lane >> 4;

  f32x4 acc[4] = {{0.f,0.f,0.f,0.f},{0.f,0.f,0.f,0.f},
                  {0.f,0.f,0.f,0.f},{0.f,0.f,0.f,0.f}};

  // staging assignment: wave 0->sAh, 1->sAl, 2->sWh, 3->sWl
  const short* gb;
  short* lb;
  int rbase;
  if (wave == 0)      { gb = Ah; lb = sAh; rbase = i0; }
  else if (wave == 1) { gb = Al; lb = sAl; rbase = i0; }
  else if (wave == 2) { gb = Wh; lb = sWh; rbase = j0; }
  else                { gb = Wl; lb = sWl; rbase = j0; }
  const int lrow8 = lane >> 3;       // 0..7 (row within 8-row issue group)
  const int spos  = lane & 7;        // linear 16B chunk within row

  for (int kt = 0; kt < CCH; kt += 64) {
    // ---- stage 4 x 8KB via global_load_lds (linear dest, swizzled source) ----
    #pragma unroll
    for (int i = 0; i < 8; ++i) {
      int row = i * 8 + lrow8;
      int gch = spos ^ (row & 7);    // inverse swizzle on global chunk
      const short* g = gb + (size_t)(rbase + row) * CCH + kt + gch * 8;
      __builtin_amdgcn_global_load_lds(
          (const __attribute__((address_space(1))) unsigned int*)g,
          (__attribute__((address_space(3))) unsigned int*)(lb + i * 512),
          16, 0, 0);
    }
    __syncthreads();
    // ---- MFMA: LDS[row][c] = G[row][c^(row&7)] -> read at c=slot^(row&7) ----
    #pragma unroll
    for (int ks = 0; ks < 2; ++ks) {
      const int arow = wave * 16 + lrow;
      const int slot = ks * 4 + lk;
      const int aoff = arow * 64 + ((slot ^ (arow & 7)) << 3);
      bf8 afh = *(const bf8*)&sAh[aoff];
      bf8 afl = *(const bf8*)&sAl[aoff];
      #pragma unroll
      for (int n = 0; n < 4; ++n) {
        const int wrow = n * 16 + lrow;
        const int woff = wrow * 64 + ((slot ^ (wrow & 7)) << 3);
        bf8 wfh = *(const bf8*)&sWh[woff];
        bf8 wfl = *(const bf8*)&sWl[woff];
        acc[n] = __builtin_amdgcn_mfma_f32_16x16x32_bf16(afh, wfh, acc[n], 0, 0, 0);
        acc[n] = __builtin_amdgcn_mfma_f32_16x16x32_bf16(afl, wfh, acc[n], 0, 0, 0);
        acc[n] = __builtin_amdgcn_mfma_f32_16x16x32_bf16(afh, wfl, acc[n], 0, 0, 0);
      }
    }
    __syncthreads();
  }
  #pragma unroll
  for (int n = 0; n < 4; ++n) {
    int j = j0 + n * 16 + lrow;
    float s  = rsqrtf(rv[j] + 1e-5f) * gg[j];
    float sh = bb[j] - rm[j] * s;
    #pragma unroll
    for (int r = 0; r < 4; ++r) {
      int row = i0 + wave * 16 + lk * 4 + r;
      if (row < M)
        out[(size_t)row * CCH + j] = 1.f + tanhf(fmaf(acc[n][r], s, sh));
    }
  }
}

// ---------------------------------------------------------------------------
// gemm2_k — MFMA with in-kernel conversion (fallback path only).
// ---------------------------------------------------------------------------
__global__ __launch_bounds__(256) void gemm2_k(
    const float* __restrict__ A0, const float* __restrict__ W0,
    const float* __restrict__ g0, const float* __restrict__ b0,
    const float* __restrict__ rm0, const float* __restrict__ rv0,
    int M0, float* __restrict__ out0,
    const float* __restrict__ A1, const float* __restrict__ W1,
    const float* __restrict__ g1, const float* __restrict__ b1,
    const float* __restrict__ rm1, const float* __restrict__ rv1,
    int M1, float* __restrict__ out1) {
  __shared__ short Ah[64*64], Al[64*64], Wh[64*64], Wl[64*64];
  const int bid = blockIdx.x;
  const float *A, *W, *gg, *bb, *rm, *rv;
  float* out;
  int M, i0, j0;
  if (bid < 10) {
    A = A0; W = W0; gg = g0; bb = b0; rm = rm0; rv = rv0; out = out0; M = M0;
    i0 = 0; j0 = bid * 64;
  } else {
    int b2 = bid - 10;
    A = A1; W = W1; gg = g1; bb = b1; rm = rm1; rv = rv1; out = out1; M = M1;
    i0 = (b2 / 10) * 64; j0 = (b2 % 10) * 64;
  }
  const int tid  = threadIdx.x;
  const int wave = tid >> 6, lane = tid & 63;
  const int lrow = lane & 15, lk = lane >> 4;
  f32x4 acc[4] = {{0.f,0.f,0.f,0.f},{0.f,0.f,0.f,0.f},
                  {0.f,0.f,0.f,0.f},{0.f,0.f,0.f,0.f}};
  const int srow0 = tid >> 3;
  const int sslot = tid & 7;
  for (int kt = 0; kt < CCH; kt += 64) {
    #pragma unroll
    for (int rnd = 0; rnd < 2; ++rnd) {
      int row  = srow0 + rnd * 32;
      int soff = row * 64 + ((sslot ^ (row & 7)) << 3);
      float a8[8];
      if (i0 + row < M) {
        const float* ap = A + (size_t)(i0 + row) * CCH + kt + sslot * 8;
        load4(a8, ap); load4(a8 + 4, ap + 4);
      } else {
        #pragma unroll
        for (int e = 0; e < 8; ++e) a8[e] = 0.f;
      }
      bf8 hv, lv;
      #pragma unroll
      for (int e = 0; e < 8; ++e) {
        unsigned short hb = bf16_rne(a8[e]);
        hv[e] = (short)hb;
        lv[e] = (short)bf16_rne(a8[e] - bfh2f(hb));
      }
      *(bf8*)&Ah[soff] = hv;
      *(bf8*)&Al[soff] = lv;
      float w8[8];
      const float* wp_ = W + (size_t)(j0 + row) * CCH + kt + sslot * 8;
      load4(w8, wp_); load4(w8 + 4, wp_ + 4);
      #pragma unroll
      for (int e = 0; e < 8; ++e) {
        unsigned short hb = bf16_rne(w8[e]);
        hv[e] = (short)hb;
        lv[e] = (short)bf16_rne(w8[e] - bfh2f(hb));
      }
      *(bf8*)&Wh[soff] = hv;
      *(bf8*)&Wl[soff] = lv;
    }
    __syncthreads();
    #pragma unroll
    for (int ks = 0; ks < 2; ++ks) {
      const int arow = wave * 16 + lrow;
      const int slot = ks * 4 + lk;
      const int aoff = arow * 64 + ((slot ^ (arow & 7)) << 3);
      bf8 afh = *(const bf8*)&Ah[aoff];
      bf8 afl = *(const bf8*)&Al[aoff];
      #pragma unroll
      for (int n = 0; n < 4; ++n) {
        const int wrow = n * 16 + lrow;
        const int woff = wrow * 64 + ((slot ^ (wrow & 7)) << 3);
        bf8 wfh = *(const bf8*)&Wh[woff];
        bf8 wfl = *(const bf8*)&Wl[woff];
        acc[n] = __builtin_amdgcn_mfma_f32_16x16x32_bf16(afh, wfh, acc[n], 0, 0, 0);
        acc[n] = __builtin_amdgcn_mfma_f32_16x16x32_bf16(afl, wfh, acc[n], 0, 0, 0);
        acc[n] = __builtin_amdgcn_mfma_f32_16x16x32_bf16(afh, wfl, acc[n], 0, 0, 0);
      }
    }
    __syncthreads();
  }
  #pragma unroll
  for (int n = 0; n < 4; ++n) {
    int j = j0 + n * 16 + lrow;
    float s  = rsqrtf(rv[j] + 1e-5f) * gg[j];
    float sh = bb[j] - rm[j] * s;
    #pragma unroll
    for (int r = 0; r < 4; ++r) {
      int row = i0 + wave * 16 + lk * 4 + r;
      if (row < M)
        out[(size_t)row * CCH + j] = 1.f + tanhf(fmaf(acc[n][r], s, sh));
    }
  }
}

// ---------------------------------------------------------------------------
// pcd_all — R11 structure (forward order; element-wise lane-pair pre-reduce).
// ---------------------------------------------------------------------------
template<bool BF>
__global__ __launch_bounds__(320, 4) void pcd_all_k(
    const float* __restrict__ spt, const float* __restrict__ qry,
    const float* __restrict__ sbuf, const float* __restrict__ qg,
    const float* __restrict__ cw_p, const float* __restrict__ cb_p,
    const float* __restrict__ cw_q, const float* __restrict__ cb_q,
    float* __restrict__ nd1f, float* __restrict__ nd2f,
    short* __restrict__ nd1h, short* __restrict__ nd1l,
    short* __restrict__ nd2h, short* __restrict__ nd2l) {
  const int blk = blockIdx.x;
  const int t = threadIdx.x;
  const float *row, *scl, *cw, *cbp;
  float* ndf; short *ndh, *ndl;
  if (blk < WSR) {
    row = spt + (size_t)blk * ROWF; scl = sbuf + (size_t)blk * CCH;
    cw = cw_p; cbp = cb_p;
    ndf = nd1f ? nd1f + (size_t)blk * CCH : nullptr;
    ndh = nd1h + (size_t)blk * CCH; ndl = nd1l + (size_t)blk * CCH;
  } else {
    int b = blk - WSR;
    row = qry + (size_t)b * ROWF; scl = qg + (size_t)b * CCH;
    cw = cw_q; cbp = cb_q;
    ndf = nd2f ? nd2f + (size_t)b * CCH : nullptr;
    ndh = nd2h + (size_t)b * CCH; ndl = nd2l + (size_t)b * CCH;
  }
  __shared__ float xps[160 * MM];    // 16 KB pair-row transpose buffer
  __shared__ float part[10][MM];
  __shared__ float pooled[2][MM];
  __shared__ float vbuf[MM];

  const float sc0 = scl[t];
  const float sc1 = scl[t + 320];
  const int tp = t >> 1;
  const bool even = !(t & 1);

  float x0[MM], x1[MM];
  {
    const float* p0 = row + t * MM;
    const float* p1 = row + (t + 320) * MM;
    float v[4];
    #pragma unroll
    for (int j = 0; j < 6; ++j) {
      load4(v, p0 + 4*j);
      x0[4*j+0] = v[0]*sc0; x0[4*j+1] = v[1]*sc0; x0[4*j+2] = v[2]*sc0; x0[4*j+3] = v[3]*sc0;
    }
    x0[24] = p0[24] * sc0;
    #pragma unroll
    for (int j = 0; j < 6; ++j) {
      load4(v, p1 + 4*j);
      x1[4*j+0] = v[0]*sc1; x1[4*j+1] = v[1]*sc1; x1[4*j+2] = v[2]*sc1; x1[4*j+3] = v[3]*sc1;
    }
    x1[24] = p1[24] * sc1;
  }

  // ---- round 1: max (element-wise pair pre-reduce, scalar temps) ----
  #pragma unroll
  for (int p = 0; p < MM; ++p) {
    float m = fmaxf(x0[p], x1[p]);
    m = fmaxf(m, __shfl_xor(m, 1));
    if (even) xps[tp*MM + p] = m;
  }
  __syncthreads();
  if (t < 250) {
    int g = t / MM, p = t - g * MM;   // g: 0..9, 16 pair-rows each
    float m = -3.4e38f;
    #pragma unroll
    for (int k = 0; k < 16; ++k) m = fmaxf(m, xps[(g*16 + k)*MM + p]);
    part[g][p] = m;
  }
  __syncthreads();
  if (t < MM) {
    float m = -3.4e38f;
    #pragma unroll
    for (int g = 0; g < 10; ++g) m = fmaxf(m, part[g][t]);
    pooled[0][t] = m;
  }
  // ---- round 2: sum ----
  #pragma unroll
  for (int p = 0; p < MM; ++p) {
    float s = x0[p] + x1[p];
    s += __shfl_xor(s, 1);
    if (even) xps[tp*MM + p] = s;
  }
  __syncthreads();
  if (t < 250) {
    int g = t / MM, p = t - g * MM;
    float s = 0.f;
    #pragma unroll
    for (int k = 0; k < 16; ++k) s += xps[(g*16 + k)*MM + p];
    part[g][p] = s;
  }
  __syncthreads();
  if (t < MM) {
    float s = 0.f;
    #pragma unroll
    for (int g = 0; g < 10; ++g) s += part[g][t];
    pooled[1][t] = s * (1.f/640.f);
  }
  __syncthreads();
  // ---- 3x3 conv + sigmoid (25 threads) ----
  if (t < MM) {
    int h = t / 5, w_ = t % 5;
    float y = cbp[0];
    #pragma unroll
    for (int ci = 0; ci < 2; ++ci)
      #pragma unroll
      for (int kh = 0; kh < 3; ++kh)
        #pragma unroll
        for (int kw = 0; kw < 3; ++kw) {
          int hh = h + kh - 1, ww = w_ + kw - 1;
          if (hh >= 0 && hh < 5 && ww >= 0 && ww < 5)
            y += pooled[ci][hh*5 + ww] * cw[ci*9 + kh*3 + kw];
        }
    vbuf[t] = 1.f / (1.f + expf(-y));
  }
  __syncthreads();
  // ---- distance from registers ----
  float d0 = 0.f, d1 = 0.f;
  #pragma unroll
  for (int p = 0; p < MM; ++p) {
    float v = vbuf[p];
    float a = x0[p] - v; d0 = fmaf(a, a, d0);
    float e = x1[p] - v; d1 = fmaf(e, e, d1);
  }
  if (BF) {
    float n0 = -d0, n1 = -d1;
    unsigned short h0 = bf16_rne(n0), h1 = bf16_rne(n1);
    ndh[t]       = (short)h0;
    ndl[t]       = (short)bf16_rne(n0 - bfh2f(h0));
    ndh[t + 320] = (short)h1;
    ndl[t + 320] = (short)bf16_rne(n1 - bfh2f(h1));
  } else {
    ndf[t]       = -d0;
    ndf[t + 320] = -d1;
  }
}

// ---------------------------------------------------------------------------
// combine (R5 form): slab-sequential streaming, NT stores.
// ---------------------------------------------------------------------------
__global__ __launch_bounds__(256) void combine_k(const float* __restrict__ wq,
    const float* __restrict__ wp, float* __restrict__ out) {
  const unsigned S4 = SLAB / 4;
  unsigned idx = blockIdx.x * 256 + threadIdx.x;
  unsigned w = idx / S4;
  unsigned rem = idx - w * S4;
  int c = (int)((rem * 4) % CCH);
  fx4 q = ((const fx4*)wq)[rem];
  fx4 p = *(const fx4*)(wp + w*CCH + c);
  fx4 o = 0.5f * (q + p);
  __builtin_nontemporal_store(o, (fx4*)out + idx);
}

__global__ __launch_bounds__(256) void combine24_k(const float* __restrict__ wq,
    const float* __restrict__ wp, float* __restrict__ out) {
  const size_t S4 = (size_t)SLAB / 4;
  size_t idx = (size_t)blockIdx.x * 256 + threadIdx.x;
  int slot = (int)(idx / S4);
  size_t rem = idx - (size_t)slot * S4;
  int w = (slot < 3) ? slot : slot + 1;
  int c = (int)((rem * 4) % CCH);
  float4 q = ((const float4*)wq)[rem];
  float4 p = *(const float4*)(wp + w*CCH + c);
  float4 o;
  o.x = 0.5f*(q.x + p.x); o.y = 0.5f*(q.y + p.y);
  o.z = 0.5f*(q.z + p.z); o.w = 0.5f*(q.w + p.w);
  ((float4*)out)[(size_t)w * S4 + rem] = o;
}

__global__ __launch_bounds__(256) void combine3_k(const float* __restrict__ wp,
                                                  float* __restrict__ out) {
  const size_t S4 = (size_t)SLAB / 4;
  size_t rem = (size_t)blockIdx.x * 256 + threadIdx.x;
  int c = (int)((rem * 4) % CCH);
  float4* ptr = (float4*)out + 3 * S4 + rem;
  float4 q = *ptr;
  float4 p = *(const float4*)(wp + 3*CCH + c);
  float4 o;
  o.x = 0.5f*(q.x + p.x); o.y = 0.5f*(q.y + p.y);
  o.z = 0.5f*(q.z + p.z); o.w = 0.5f*(q.w + p.w);
  *ptr = o;
}

// ---------------------------------------------------------------------------
extern "C" void kernel_launch(void* const* d_in, const int* in_sizes, int n_in,
                              void* d_out, int out_size, void* d_ws, size_t ws_size,
                              hipStream_t stream) {
  const float* spt    = (const float*)d_in[0];
  const float* qry    = (const float*)d_in[1];
  const float* W_p    = (const float*)d_in[2];
  const float* g_p    = (const float*)d_in[3];
  const float* b_p    = (const float*)d_in[4];
  const float* rm_p   = (const float*)d_in[5];
  const float* rv_p   = (const float*)d_in[6];
  const float* W_q    = (const float*)d_in[7];
  const float* g_q    = (const float*)d_in[8];
  const float* b_q    = (const float*)d_in[9];
  const float* rm_q   = (const float*)d_in[10];
  const float* rv_q   = (const float*)d_in[11];
  const float* W_prt  = (const float*)d_in[12];
  const float* g_prt  = (const float*)d_in[13];
  const float* b_prt  = (const float*)d_in[14];
  const float* rm_prt = (const float*)d_in[15];
  const float* rv_prt = (const float*)d_in[16];
  const float* W_qs   = (const float*)d_in[17];
  const float* g_qs   = (const float*)d_in[18];
  const float* b_qs   = (const float*)d_in[19];
  const float* rm_qs  = (const float*)d_in[20];
  const float* rv_qs  = (const float*)d_in[21];
  const float* cw_p   = (const float*)d_in[22];
  const float* cb_p   = (const float*)d_in[23];
  const float* cw_q   = (const float*)d_in[24];
  const float* cb_q   = (const float*)d_in[25];

  float* outp = (float*)d_out;
  float* ws   = (float*)d_ws;

  dim3 blk(256);
  dim3 blkp(320);

  const size_t fl_count = 32000 + 2*(size_t)SLAB;
  const size_t sh_count = 4*16000 + 4*(size_t)SLAB + 8*(size_t)WELEM;
  const size_t need = fl_count*sizeof(float) + sh_count*sizeof(short);
  const bool big_ws = ws_size >= need;

  if (big_ws) {
    float* sbuf = ws;
    float* wprt = ws + 16000;
    float* qg   = ws + 32000;
    float* wqry = ws + 32000 + (size_t)SLAB;
    short* sp   = (short*)(ws + fl_count);
    short* pmh  = sp;            short* pml  = sp + 16000;
    short* nd1h = sp + 32000;    short* nd1l = sp + 48000;
    short* qmh  = sp + 64000;
    short* qml  = qmh + (size_t)SLAB;
    short* nd2h = qml + (size_t)SLAB;
    short* nd2l = nd2h + (size_t)SLAB;
    short* wph  = nd2l + (size_t)SLAB;
    short* wpl  = wph + WELEM;
    short* wqh  = wpl + WELEM;  short* wql = wqh + WELEM;
    short* wrh  = wql + WELEM;  short* wrl = wrh + WELEM;
    short* wsh  = wrl + WELEM;  short* wsl = wsh + WELEM;

    prep_k<<<NMEAN_B + NW_B, blk, 0, stream>>>(spt, qry, W_p, W_q, W_prt, W_qs,
        pmh, pml, qmh, qml, wph, wpl, wqh, wql, wrh, wrl, wsh, wsl);
    gemm2_bf_k<<<650, blk, 0, stream>>>(
        pmh, pml, wph, wpl, g_p, b_p, rm_p, rv_p, WSR, sbuf,
        qmh, qml, wqh, wql, g_q, b_q, rm_q, rv_q, NB, qg);
    pcd_all_k<true><<<WSR + NB, blkp, 0, stream>>>(spt, qry, sbuf, qg,
        cw_p, cb_p, cw_q, cb_q, nullptr, nullptr, nd1h, nd1l, nd2h, nd2l);
    gemm2_bf_k<<<650, blk, 0, stream>>>(
        nd1h, nd1l, wrh, wrl, g_prt, b_prt, rm_prt, rv_prt, WSR, wprt,
        nd2h, nd2l, wsh, wsl, g_qs, b_qs, rm_qs, rv_qs, NB, wqry);
    combine_k<<<25 * (SLAB/4) / 256, blk, 0, stream>>>(wqry, wprt, outp);
  } else {
    // fallback: R8 pipeline staged in d_out slabs + small ws buffers
    float* pmean  = ws;
    float* sbuf   = ws + 16000;
    float* ndist1 = ws + 32000;
    float* wprt   = ws + 48000;
    float* qmean  = outp + 0 * (size_t)SLAB;
    float* qg     = outp + 1 * (size_t)SLAB;
    float* ndist2 = outp + 2 * (size_t)SLAB;
    float* wqry   = outp + 3 * (size_t)SLAB;
    const int nmean = (WSR + NB) * CCH;
    rowmean_all_k<<<(nmean + 255)/256, blk, 0, stream>>>(spt, qry, pmean, qmean, nmean);
    gemm2_k<<<650, blk, 0, stream>>>(pmean, W_p, g_p, b_p, rm_p, rv_p, WSR, sbuf,
                                     qmean, W_q, g_q, b_q, rm_q, rv_q, NB, qg);
    pcd_all_k<false><<<WSR + NB, blkp, 0, stream>>>(spt, qry, sbuf, qg,
        cw_p, cb_p, cw_q, cb_q, ndist1, ndist2,
        (short*)ws, (short*)ws, (short*)ws, (short*)ws);
    gemm2_k<<<650, blk, 0, stream>>>(ndist1, W_prt, g_prt, b_prt, rm_prt, rv_prt, WSR, wprt,
                                     ndist2, W_qs, g_qs, b_qs, rm_qs, rv_qs, NB, wqry);
    combine24_k<<<(24 * (SLAB/4)) / 256, blk, 0, stream>>>(wqry, wprt, outp);
    combine3_k<<<(SLAB/4) / 256, blk, 0, stream>>>(wprt, outp);
  }
}